// Round 4
// baseline (189.617 us; speedup 1.0000x reference)
//
#include <hip/hip_runtime.h>
#include <hip/hip_bf16.h>

#define N_SRCN 200000
#define N_DSTN 50000
#define NEDGE 800000
#define KIN 256
#define NF 192        // H*OUT = 3*64
#define SLOPE 0.2f

typedef __attribute__((ext_vector_type(8))) short bf16x8;
typedef __attribute__((ext_vector_type(4))) float f32x4;

__device__ __forceinline__ unsigned short f2bf(float f) {
    union { float f; unsigned int u; } v; v.f = f;
    unsigned int u = v.u;
    return (unsigned short)((u + 0x7FFFu + ((u >> 16) & 1u)) >> 16);  // RNE
}
__device__ __forceinline__ float bf2f(unsigned short h) {
    union { unsigned int u; float f; } v; v.u = ((unsigned int)h) << 16;
    return v.f;
}
__device__ __forceinline__ unsigned int cvt2(float lo, float hi) {
    __hip_bfloat162 h = __float22bfloat162_rn(float2{lo, hi});
    union { __hip_bfloat162 h; unsigned int u; } c; c.h = h;
    return c.u;
}
__device__ __forceinline__ void gl_lds16(const void* g, void* l) {
    __builtin_amdgcn_global_load_lds(
        (const __attribute__((address_space(1))) unsigned int*)g,
        (__attribute__((address_space(3))) unsigned int*)l, 16, 0, 0);
}

// ---------------- prep: pack W (f32 [192][256]) into bf16 fragment-major -----
__global__ void prep_w(const float* __restrict__ W, unsigned short* __restrict__ Wp) {
    int tid = blockIdx.x * blockDim.x + threadIdx.x;
    if (tid >= 12 * 8 * 64) return;
    int lane = tid & 63;
    int g = tid >> 6;
    int nt = g % 12, ks = g / 12;
    int col = nt * 16 + (lane & 15);
    int k = ks * 32 + (lane >> 4) * 8;
    const float* wsrc = &W[col * KIN + k];
    unsigned short* o = &Wp[tid * 8];
    #pragma unroll
    for (int j = 0; j < 8; ++j) o[j] = f2bf(wsrc[j]);
}

// ---------------- row_ptr: lower_bound of each d in sorted dst ----------------
__global__ void rowptr_kernel(const int* __restrict__ dst, int* __restrict__ rp) {
    int d = blockIdx.x * blockDim.x + threadIdx.x;
    if (d > N_DSTN) return;
    int lo = 0, hi = NEDGE;
    while (lo < hi) {
        int mid = (lo + hi) >> 1;
        if (dst[mid] < d) lo = mid + 1; else hi = mid;
    }
    rp[d] = lo;
}

// ---------------- GEMM: feat = x @ W^T (bf16 MFMA) + fused el/er -------------
// 64-row block, 4 waves; x staged f32 into LDS via global_load_lds DMA in two
// K-halves with counted vmcnt (compute h0 while h1 loads in flight). 16B-quad
// XOR swizzle applied on the GLOBAL source and on the LDS read (rule #21).
__launch_bounds__(256, 2)
__global__ void gemm_feat(const float* __restrict__ x, const unsigned short* __restrict__ Wp,
                          const float* __restrict__ attn_l, const float* __restrict__ attn_r,
                          unsigned short* __restrict__ feat,
                          float* __restrict__ el, float* __restrict__ er) {
    __shared__ float lds[2][64][128];   // 64 KB
    const int t = threadIdx.x;
    const int wid = t >> 6, lane = t & 63;
    const int al = lane & 15, ah = lane >> 4;
    const int r0g = blockIdx.x * 64;
    const int wrow0 = wid * 16;

    // ---- stage: wave w stages rows [w*16, w*16+16), 2 rows (1KB) per DMA call
    #pragma unroll
    for (int h = 0; h < 2; ++h) {
        #pragma unroll
        for (int rr = 0; rr < 16; rr += 2) {
            const int rl = wrow0 + rr + (lane >> 5);   // local row fed by this lane
            const int qq = lane & 31;                  // 16B quad within row-half
            const int swz = rl & 7;
            const float* gp = &x[(size_t)(r0g + rl) * KIN + h * 128 + ((qq ^ swz) << 2)];
            gl_lds16(gp, &lds[h][wrow0 + rr][0]);
        }
        __builtin_amdgcn_sched_barrier(0);             // pin h0-group before h1-group
    }

    f32x4 acc[12] = {};
    const int rl = wrow0 + al;
    const int swz = rl & 7;
    const char* abase = (const char*)&lds[0][rl][0];

    #pragma unroll
    for (int half = 0; half < 2; ++half) {
        if (half == 0) { asm volatile("s_waitcnt vmcnt(8)" ::: "memory"); }
        else           { asm volatile("s_waitcnt vmcnt(0)" ::: "memory"); }
        __builtin_amdgcn_s_barrier();
        __builtin_amdgcn_sched_barrier(0);
        #pragma unroll
        for (int ksl = 0; ksl < 4; ++ksl) {
            const int q0 = ksl * 8 + ah * 2;
            const char* b = abase + (size_t)half * 64 * 128 * 4;
            const float4 v0 = *(const float4*)(b + ((q0 ^ swz) * 16));
            const float4 v1 = *(const float4*)(b + (((q0 + 1) ^ swz) * 16));
            union { bf16x8 v; unsigned int u[4]; } av;
            av.u[0] = cvt2(v0.x, v0.y);
            av.u[1] = cvt2(v0.z, v0.w);
            av.u[2] = cvt2(v1.x, v1.y);
            av.u[3] = cvt2(v1.z, v1.w);
            const int ks = half * 4 + ksl;
            const unsigned short* wbase = &Wp[(size_t)(ks * 12) * 512 + lane * 8];
            #pragma unroll
            for (int nt = 0; nt < 12; ++nt) {
                bf16x8 bv = *(const bf16x8*)&wbase[nt * 512];
                acc[nt] = __builtin_amdgcn_mfma_f32_16x16x32_bf16(av.v, bv, acc[nt], 0, 0, 0);
            }
        }
    }

    // epilogue 1: feat store (C/D layout: col=al+nt*16, row=ah*4+e  [m89])
    #pragma unroll
    for (int nt = 0; nt < 12; ++nt) {
        const int col = nt * 16 + al;
        #pragma unroll
        for (int e = 0; e < 4; ++e) {
            const int row = r0g + wrow0 + ah * 4 + e;
            feat[(size_t)row * NF + col] = f2bf(acc[nt][e]);
        }
    }

    // epilogue 2: fused el/er
    float Al[12], Ar[12];
    #pragma unroll
    for (int nt = 0; nt < 12; ++nt) {
        Al[nt] = attn_l[nt * 16 + al];
        Ar[nt] = attn_r[nt * 16 + al];
    }
    #pragma unroll
    for (int h = 0; h < 3; ++h) {
        #pragma unroll
        for (int e = 0; e < 4; ++e) {
            float sl = 0.f, sr = 0.f;
            #pragma unroll
            for (int q = 0; q < 4; ++q) {
                const int nt = h * 4 + q;
                sl += acc[nt][e] * Al[nt];
                sr += acc[nt][e] * Ar[nt];
            }
            #pragma unroll
            for (int m = 1; m <= 8; m <<= 1) {
                sl += __shfl_xor(sl, m);
                sr += __shfl_xor(sr, m);
            }
            if (al == 0) {
                const int row = r0g + wrow0 + ah * 4 + e;
                el[row * 3 + h] = sl;
                if (row < N_DSTN) er[row * 3 + h] = sr;
            }
        }
    }
}

// ---------------- gather: edge softmax (no max shift) + weighted accumulate --
__launch_bounds__(256)
__global__ void gather_kernel(const unsigned short* __restrict__ feat,
                              const float* __restrict__ el, const float* __restrict__ er,
                              const int* __restrict__ src, const int* __restrict__ rp,
                              float* __restrict__ out) {
    const int lane = threadIdx.x & 63;
    const int d = (blockIdx.x * blockDim.x + threadIdx.x) >> 6;
    if (d >= N_DSTN) return;
    const int lo = rp[d], hi = rp[d + 1];
    const float er0 = er[d * 3 + 0], er1 = er[d * 3 + 1], er2 = er[d * 3 + 2];

    float a0 = 0.f, a1 = 0.f, a2 = 0.f, s0 = 0.f, s1 = 0.f, s2 = 0.f;
    for (int base = lo; base < hi; base += 64) {
        const int cnt = min(64, hi - base);
        int sv = 0; float w0 = 0.f, w1 = 0.f, w2 = 0.f;
        if (lane < cnt) {
            sv = src[base + lane];
            float e0 = el[sv * 3 + 0] + er0; e0 = e0 >= 0.f ? e0 : SLOPE * e0; w0 = __expf(e0);
            float e1 = el[sv * 3 + 1] + er1; e1 = e1 >= 0.f ? e1 : SLOPE * e1; w1 = __expf(e1);
            float e2 = el[sv * 3 + 2] + er2; e2 = e2 >= 0.f ? e2 : SLOPE * e2; w2 = __expf(e2);
        }
        int j = 0;
        for (; j + 8 <= cnt; j += 8) {
            unsigned short f0[8], f1[8], f2[8];
            float u0[8], u1[8], u2[8];
            #pragma unroll
            for (int q = 0; q < 8; ++q) {
                const int sj = __shfl(sv, j + q);
                const unsigned short* fp = &feat[(size_t)sj * NF + lane];
                f0[q] = fp[0]; f1[q] = fp[64]; f2[q] = fp[128];
                u0[q] = __shfl(w0, j + q);
                u1[q] = __shfl(w1, j + q);
                u2[q] = __shfl(w2, j + q);
            }
            #pragma unroll
            for (int q = 0; q < 8; ++q) {
                s0 += u0[q]; a0 += u0[q] * bf2f(f0[q]);
                s1 += u1[q]; a1 += u1[q] * bf2f(f1[q]);
                s2 += u2[q]; a2 += u2[q] * bf2f(f2[q]);
            }
        }
        for (; j < cnt; ++j) {
            const int sj = __shfl(sv, j);
            const float u0 = __shfl(w0, j);
            const float u1 = __shfl(w1, j);
            const float u2 = __shfl(w2, j);
            const unsigned short* fp = &feat[(size_t)sj * NF + lane];
            s0 += u0; a0 += u0 * bf2f(fp[0]);
            s1 += u1; a1 += u1 * bf2f(fp[64]);
            s2 += u2; a2 += u2 * bf2f(fp[128]);
        }
    }
    if (hi == lo) { s0 = 1.f; s1 = 1.f; s2 = 1.f; }
    float* op = &out[(size_t)d * NF];
    op[lane]       = a0 / s0;
    op[64 + lane]  = a1 / s1;
    op[128 + lane] = a2 / s2;
}

extern "C" void kernel_launch(void* const* d_in, const int* in_sizes, int n_in,
                              void* d_out, int out_size, void* d_ws, size_t ws_size,
                              hipStream_t stream) {
    const float* x      = (const float*)d_in[0];
    const float* W      = (const float*)d_in[1];
    const float* attn_l = (const float*)d_in[2];
    const float* attn_r = (const float*)d_in[3];
    const int*   src    = (const int*)d_in[4];
    const int*   dst    = (const int*)d_in[5];
    float* out = (float*)d_out;

    char* ws = (char*)d_ws;
    unsigned short* feat = (unsigned short*)ws;             // 76,800,000 B
    float* el = (float*)(ws + 76800000);                    //  2,400,000 B
    float* er = (float*)(ws + 79200000);                    //    600,000 B
    unsigned short* Wp = (unsigned short*)(ws + 79800000);  //     98,304 B
    int*   rp = (int*)(ws + 79898304);                      //    200,004 B

    prep_w<<<24, 256, 0, stream>>>(W, Wp);
    rowptr_kernel<<<(N_DSTN + 1 + 255) / 256, 256, 0, stream>>>(dst, rp);
    gemm_feat<<<3125, 256, 0, stream>>>(x, Wp, attn_l, attn_r, feat, el, er);
    gather_kernel<<<12500, 256, 0, stream>>>(feat, el, er, src, rp, out);
}